// Round 12
// baseline (198.199 us; speedup 1.0000x reference)
//
#include <hip/hip_runtime.h>
#include <hip/hip_bf16.h>
#include <stdint.h>

// B=2, S=4096, D=512, H=8, dk=64. fp32 in/out, bf16 MFMA internals.
// R12: non-attn was the bottleneck (qkv+proj ~90us = ~190 TF, m93-rung).
//  - ln grid tail pre-converts all 4 weights fp32->bf16 (Wb, ws+32MB).
//  - qkv/proj staging via __builtin_amdgcn_global_load_lds width=16
//    (m93->m97 = 517->874 TF move): kills VGPR round-trip + LDS write pass
//    + cvt VALU. Linear LDS (no swizzle possible) -> fragment b128 reads at
//    2x bank cost (16 vs 8 cyc) — net big win.
//  - attn unchanged from R11 (82.8us, MfmaUtil 39.5 + VALU 43.5 = 83%).

typedef __bf16 bf16;
typedef __attribute__((ext_vector_type(8))) __bf16 bf16x8;
typedef __attribute__((ext_vector_type(4))) __bf16 bf16x4;
typedef __attribute__((ext_vector_type(4))) float f32x4;
typedef __attribute__((ext_vector_type(4))) unsigned int u32x4;

#define LOG2E 1.44269504088896340736f
// Swizzled elem offset of an 8-elem group in a [rows][64] bf16 LDS tile
// (used by attn only; global_load_lds tiles are linear).
#define SW(row, grp) (((row) << 6) + ((((grp) ^ ((row) & 7))) << 3))

__device__ __forceinline__ void gl2lds16(const void* g, void* l) {
  // async global->LDS, 16B/lane; LDS dest = wave-uniform base + lane*16.
  __builtin_amdgcn_global_load_lds(
      (__attribute__((address_space(1))) void*)(uintptr_t)g,
      (__attribute__((address_space(3))) void*)(l), 16, 0, 0);
}

// pack two f32 into (bf16(hi)<<16)|bf16(lo) by hi-16 truncation (RTZ)
__device__ __forceinline__ unsigned int pkbf16(float lo, float hi) {
  return __builtin_amdgcn_perm(__builtin_bit_cast(unsigned int, hi),
                               __builtin_bit_cast(unsigned int, lo),
                               0x07060302u);
}

// ------------------------------------- LayerNorm + weight-convert tail
// blocks 0..2047: LN rows. blocks 2048..2559: convert 4 weights to bf16.
__global__ __launch_bounds__(256) void ln_kernel(
    const float* __restrict__ x, const float* __restrict__ gamma,
    const float* __restrict__ beta, const float* __restrict__ wq,
    const float* __restrict__ wk, const float* __restrict__ wv,
    const float* __restrict__ wo, bf16* __restrict__ h,
    bf16* __restrict__ Wb) {
  if (blockIdx.x >= 2048) {             // weight conversion: 2048 elems/block
    int base = (blockIdx.x - 2048) * 2048 + threadIdx.x * 8;
    int w = base >> 18;                 // 262144 elems per weight
    const float* src = (w == 0) ? wq : (w == 1) ? wk : (w == 2) ? wv : wo;
    int off = base & 262143;
    f32x4 a = *(const f32x4*)(src + off);
    f32x4 b = *(const f32x4*)(src + off + 4);
    bf16x8 o;
#pragma unroll
    for (int i = 0; i < 4; ++i) { o[i] = (bf16)a[i]; o[4 + i] = (bf16)b[i]; }
    *(bf16x8*)(Wb + base) = o;
    return;
  }
  int wave = threadIdx.x >> 6, lane = threadIdx.x & 63;
  int row = blockIdx.x * 4 + wave;                 // 8192 rows
  const float* xr = x + (size_t)row * 512 + lane * 8;
  f32x4 v0 = *(const f32x4*)xr;
  f32x4 v1 = *(const f32x4*)(xr + 4);
  float f[8], s = 0.f, s2 = 0.f;
#pragma unroll
  for (int i = 0; i < 4; ++i) { f[i] = v0[i]; f[4 + i] = v1[i]; }
#pragma unroll
  for (int i = 0; i < 8; ++i) { s += f[i]; s2 += f[i] * f[i]; }
#pragma unroll
  for (int off = 1; off < 64; off <<= 1) {
    s  += __shfl_xor(s, off, 64);
    s2 += __shfl_xor(s2, off, 64);
  }
  float mu  = s * (1.f / 512.f);
  float var = s2 * (1.f / 512.f) - mu * mu;
  float rstd = rsqrtf(var + 1e-5f);
  f32x4 g0 = *(const f32x4*)(gamma + lane * 8);
  f32x4 g1 = *(const f32x4*)(gamma + lane * 8 + 4);
  f32x4 b0 = *(const f32x4*)(beta + lane * 8);
  f32x4 b1 = *(const f32x4*)(beta + lane * 8 + 4);
  bf16x8 o;
#pragma unroll
  for (int i = 0; i < 4; ++i) {
    o[i]     = (bf16)((f[i]     - mu) * rstd * g0[i] + b0[i]);
    o[4 + i] = (bf16)((f[4 + i] - mu) * rstd * g1[i] + b1[i]);
  }
  *(bf16x8*)(h + (size_t)row * 512 + lane * 8) = o;
}

// ------------------------------------------------------------- QKV GEMM
// Staging: global_load_lds width=16, linear LDS [128][64] (m97 pattern).
__global__ __launch_bounds__(256) void qkv_kernel(
    const bf16* __restrict__ h, const bf16* __restrict__ Wb,
    bf16* __restrict__ Qg, bf16* __restrict__ Kg, bf16* __restrict__ Vtg) {
  __shared__ bf16 As[128 * 64];
  __shared__ bf16 Bs[128 * 64];
  int tid = threadIdx.x, wave = tid >> 6, lane = tid & 63;
  int wm = wave >> 1, wn = wave & 1, quad = lane >> 4, l15 = lane & 15;
  int mtile = blockIdx.x;          // 0..63
  int wsel = blockIdx.y >> 2;      // 0=q 1=k 2=v
  int nb = blockIdx.y & 3;
  const bf16* Abase = h + (size_t)mtile * 128 * 512;
  const bf16* Bbase = Wb + (size_t)wsel * 262144 + (size_t)nb * 128 * 512;
  f32x4 acc[4][4];
#pragma unroll
  for (int i = 0; i < 4; ++i)
#pragma unroll
    for (int j = 0; j < 4; ++j) acc[i][j] = (f32x4){0.f, 0.f, 0.f, 0.f};

  int gr = lane >> 3, gc = (lane & 7) * 8;   // per-lane global row/col in 1KB
  for (int k0 = 0; k0 < 512; k0 += 64) {
#pragma unroll
    for (int j = 0; j < 4; ++j) {            // each wave stages 32 rows of A,B
      int r0 = wave * 32 + j * 8;
      gl2lds16(Abase + (size_t)(r0 + gr) * 512 + k0 + gc, As + r0 * 64);
      gl2lds16(Bbase + (size_t)(r0 + gr) * 512 + k0 + gc, Bs + r0 * 64);
    }
    __builtin_amdgcn_s_waitcnt(0);
    __syncthreads();
#pragma unroll
    for (int c = 0; c < 2; ++c) {
      bf16x8 af[4], bw[4];
#pragma unroll
      for (int mt = 0; mt < 4; ++mt)
        af[mt] = *(const bf16x8*)(As + (wm * 64 + mt * 16 + l15) * 64 +
                                  c * 32 + quad * 8);
#pragma unroll
      for (int nt = 0; nt < 4; ++nt)
        bw[nt] = *(const bf16x8*)(Bs + (wn * 64 + nt * 16 + l15) * 64 +
                                  c * 32 + quad * 8);
#pragma unroll
      for (int mt = 0; mt < 4; ++mt)
#pragma unroll
        for (int nt = 0; nt < 4; ++nt)
          acc[mt][nt] = __builtin_amdgcn_mfma_f32_16x16x32_bf16(
              bw[nt], af[mt], acc[mt][nt], 0, 0, 0);
    }
    __syncthreads();
  }
  // Q pre-scale folds softmax 1/sqrt(64) AND log2(e) for exp2-based softmax.
  float qscale = (wsel == 0) ? (0.125f * LOG2E) : 1.0f;
#pragma unroll
  for (int mt = 0; mt < 4; ++mt) {
    int m_g = mtile * 128 + wm * 64 + mt * 16 + l15;   // token
    int b = m_g >> 12, s = m_g & 4095;
#pragma unroll
    for (int nt = 0; nt < 4; ++nt) {
      int n_g = nb * 128 + wn * 64 + nt * 16 + quad * 4;  // feature
      int head = n_g >> 6, d = n_g & 63;
      f32x4 a = acc[mt][nt];
      if (wsel < 2) {
        bf16* dst = (wsel == 0 ? Qg : Kg) +
                    ((size_t)((b * 8 + head) * 4096 + s)) * 64 + d;
        bf16x4 pk;
#pragma unroll
        for (int r = 0; r < 4; ++r) pk[r] = (bf16)(a[r] * qscale);
        *(bf16x4*)dst = pk;
      } else {
        bf16* dst = Vtg + ((size_t)((b * 8 + head) * 64 + d)) * 4096 + s;
#pragma unroll
        for (int r = 0; r < 4; ++r) dst[(size_t)r * 4096] = (bf16)a[r];
      }
    }
  }
}

// --------------------------------------------------------- Flash attention
// (unchanged from R11 — 82.8us, issue-bound at 83% combined pipes)
__global__ __launch_bounds__(256, 2) void attn_kernel(
    const bf16* __restrict__ Qg, const bf16* __restrict__ Kg,
    const bf16* __restrict__ Vtg, bf16* __restrict__ Og) {
  __shared__ char smem[64 * 1024];
  bf16* KV = (bf16*)smem;               // [buf][khalf][K 4096 | V 4096]
  float* OL = (float*)smem;             // merge (post-loop alias): 2x4096 f32
  float* Ll = (float*)(smem + 49152);   // merge l: 128 f32 (post-loop alias)

  int tid = threadIdx.x, wave = tid >> 6, lane = tid & 63;
  int quad = lane >> 4, l15 = lane & 15;
  int qgrp = wave & 1, khalf = wave >> 1;
  int lin = blockIdx.x;                 // 0..511, XCD-aware decode
  int bh = ((lin & 7) << 1) | ((lin >> 3) & 1);
  int q0 = (lin >> 4) * 128;
  int hi = bh & 7, bi = bh >> 3;
  const bf16* Kh  = Kg  + (size_t)bh * 4096 * 64;
  const bf16* Vth = Vtg + (size_t)bh * 64 * 4096;

  bf16x8 qf[4][2];   // Q pre-scaled by 0.125*LOG2E in qkv
#pragma unroll
  for (int mt = 0; mt < 4; ++mt)
#pragma unroll
    for (int c = 0; c < 2; ++c)
      qf[mt][c] = *(const bf16x8*)(
          Qg + ((size_t)bh * 4096 + q0 + qgrp * 64 + mt * 16 + l15) * 64 +
          c * 32 + quad * 8);

  f32x4 o_acc[4][4], lacc[4];
#pragma unroll
  for (int mt = 0; mt < 4; ++mt) {
    lacc[mt] = (f32x4){0.f, 0.f, 0.f, 0.f};
#pragma unroll
    for (int nt = 0; nt < 4; ++nt) o_acc[mt][nt] = (f32x4){0.f, 0.f, 0.f, 0.f};
  }
  const u32x4 onesu = {0x3F803F80u, 0x3F803F80u, 0x3F803F80u, 0x3F803F80u};
  const bf16x8 ones8 = __builtin_bit_cast(bf16x8, onesu);

  bf16* sbase = KV + khalf * 8192 + (qgrp ? 4096 : 0);
  bf16x8 sr[8];
  int key0 = khalf * 2048;
#pragma unroll
  for (int i = 0; i < 8; ++i) {          // tile 0
    int e = i * 512 + lane * 8;
    sr[i] = qgrp
        ? *(const bf16x8*)(Vth + (size_t)(e >> 6) * 4096 + key0 + (e & 63))
        : *(const bf16x8*)(Kh + (size_t)key0 * 64 + e);
  }
#pragma unroll
  for (int i = 0; i < 8; ++i) {          // write tile 0 -> buf0
    int e = i * 512 + lane * 8;
    *(bf16x8*)(sbase + SW(e >> 6, (e >> 3) & 7)) = sr[i];
  }
#pragma unroll
  for (int i = 0; i < 8; ++i) {          // prefetch tile 1
    int e = i * 512 + lane * 8;
    sr[i] = qgrp
        ? *(const bf16x8*)(Vth + (size_t)(e >> 6) * 4096 + key0 + 64 + (e & 63))
        : *(const bf16x8*)(Kh + (size_t)(key0 + 64) * 64 + e);
  }
  __syncthreads();

  for (int kt = 0; kt < 32; ++kt) {
    int cur = kt & 1, nxt = cur ^ 1;
    bf16* Ksw = KV + cur * 16384 + khalf * 8192;
    bf16* Vsw = Ksw + 4096;
    if (kt < 31) {                       // stage tile kt+1 -> other buffer
#pragma unroll
      for (int i = 0; i < 8; ++i) {
        int e = i * 512 + lane * 8;
        *(bf16x8*)(sbase + nxt * 16384 + SW(e >> 6, (e >> 3) & 7)) = sr[i];
      }
    }
    if (kt < 30) {                       // prefetch tile kt+2
      int kbase = key0 + (kt + 2) * 64;
#pragma unroll
      for (int i = 0; i < 8; ++i) {
        int e = i * 512 + lane * 8;
        sr[i] = qgrp
            ? *(const bf16x8*)(Vth + (size_t)(e >> 6) * 4096 + kbase + (e & 63))
            : *(const bf16x8*)(Kh + (size_t)kbase * 64 + e);
      }
    }
    bf16x8 kf[8];
#pragma unroll
    for (int kb = 0; kb < 4; ++kb)
#pragma unroll
      for (int c = 0; c < 2; ++c)
        kf[kb * 2 + c] = *(const bf16x8*)(Ksw + SW(kb * 16 + l15, c * 4 + quad));
    bf16x8 vf8[2][4];
#pragma unroll
    for (int pr = 0; pr < 2; ++pr)
#pragma unroll
      for (int nt = 0; nt < 4; ++nt) {
        bf16x4 lo = *(const bf16x4*)(
            &Vsw[SW(nt * 16 + l15, (pr * 2) * 2 + (quad >> 1)) + (quad & 1) * 4]);
        bf16x4 hi4 = *(const bf16x4*)(
            &Vsw[SW(nt * 16 + l15, (pr * 2 + 1) * 2 + (quad >> 1)) + (quad & 1) * 4]);
        bf16x8 v;
#pragma unroll
        for (int j = 0; j < 4; ++j) { v[j] = lo[j]; v[4 + j] = hi4[j]; }
        vf8[pr][nt] = v;
      }
#pragma unroll
    for (int mt = 0; mt < 4; ++mt) {
      f32x4 st[4];
#pragma unroll
      for (int kb = 0; kb < 4; ++kb) st[kb] = (f32x4){0.f, 0.f, 0.f, 0.f};
#pragma unroll
      for (int c = 0; c < 2; ++c)
#pragma unroll
        for (int kb = 0; kb < 4; ++kb)
          st[kb] = __builtin_amdgcn_mfma_f32_16x16x32_bf16(
              kf[kb * 2 + c], qf[mt][c], st[kb], 0, 0, 0);
#pragma unroll
      for (int pr = 0; pr < 2; ++pr) {
        float ea[4], eb[4];
#pragma unroll
        for (int r = 0; r < 4; ++r) {
          ea[r] = __builtin_amdgcn_exp2f(st[pr * 2][r]);
          eb[r] = __builtin_amdgcn_exp2f(st[pr * 2 + 1][r]);
        }
        u32x4 pw = {pkbf16(ea[0], ea[1]), pkbf16(ea[2], ea[3]),
                    pkbf16(eb[0], eb[1]), pkbf16(eb[2], eb[3])};
        bf16x8 pk8 = __builtin_bit_cast(bf16x8, pw);
#pragma unroll
        for (int nt = 0; nt < 4; ++nt)
          o_acc[mt][nt] = __builtin_amdgcn_mfma_f32_16x16x32_bf16(
              vf8[pr][nt], pk8, o_acc[mt][nt], 0, 0, 0);
        lacc[mt] = __builtin_amdgcn_mfma_f32_16x16x32_bf16(
            ones8, pk8, lacc[mt], 0, 0, 0);
      }
    }
    __syncthreads();
  }
  if (khalf == 1) {
    float* dst = OL + qgrp * 4096;
#pragma unroll
    for (int mt = 0; mt < 4; ++mt) {
#pragma unroll
      for (int nt = 0; nt < 4; ++nt) {
        int row = mt * 16 + l15;
        int g = nt * 4 + quad;
        int gs = (g & 8) | ((g ^ row) & 7);
        *(f32x4*)(&dst[row * 64 + gs * 4]) = o_acc[mt][nt];
      }
      if (quad == 0) Ll[qgrp * 64 + mt * 16 + l15] = lacc[mt][0];
    }
  }
  __syncthreads();
  if (khalf == 0) {
    const float* src = OL + qgrp * 4096;
#pragma unroll
    for (int mt = 0; mt < 4; ++mt) {
      float lt = lacc[mt][0] + Ll[qgrp * 64 + mt * 16 + l15];
      float inv = 1.0f / lt;
      int q = q0 + qgrp * 64 + mt * 16 + l15;
#pragma unroll
      for (int nt = 0; nt < 4; ++nt) {
        int row = mt * 16 + l15;
        int g = nt * 4 + quad;
        int gs = (g & 8) | ((g ^ row) & 7);
        f32x4 o = *(const f32x4*)(&src[row * 64 + gs * 4]);
        bf16x4 pk;
#pragma unroll
        for (int r = 0; r < 4; ++r)
          pk[r] = (bf16)((o[r] + o_acc[mt][nt][r]) * inv);
        *(bf16x4*)(&Og[((size_t)bi * 4096 + q) * 512 + hi * 64 + nt * 16 +
                       quad * 4]) = pk;
      }
    }
  }
}

// ----------------------------------------------- out = A @ Wo^T + bo + x
// Staging via global_load_lds (Wo pre-converted to bf16 in Wb[3]).
__global__ __launch_bounds__(256) void proj_kernel(
    const bf16* __restrict__ A, const bf16* __restrict__ Wob,
    const float* __restrict__ bo, const float* __restrict__ x,
    float* __restrict__ out) {
  __shared__ bf16 As[128 * 64];
  __shared__ bf16 Bs[128 * 64];
  int tid = threadIdx.x, wave = tid >> 6, lane = tid & 63;
  int wm = wave >> 1, wn = wave & 1, quad = lane >> 4, l15 = lane & 15;
  int mtile = blockIdx.x, nb = blockIdx.y;
  const bf16* Abase = A + (size_t)mtile * 128 * 512;
  const bf16* Bbase = Wob + (size_t)nb * 128 * 512;
  f32x4 acc[4][4];
#pragma unroll
  for (int i = 0; i < 4; ++i)
#pragma unroll
    for (int j = 0; j < 4; ++j) acc[i][j] = (f32x4){0.f, 0.f, 0.f, 0.f};

  int gr = lane >> 3, gc = (lane & 7) * 8;
  for (int k0 = 0; k0 < 512; k0 += 64) {
#pragma unroll
    for (int j = 0; j < 4; ++j) {
      int r0 = wave * 32 + j * 8;
      gl2lds16(Abase + (size_t)(r0 + gr) * 512 + k0 + gc, As + r0 * 64);
      gl2lds16(Bbase + (size_t)(r0 + gr) * 512 + k0 + gc, Bs + r0 * 64);
    }
    __builtin_amdgcn_s_waitcnt(0);
    __syncthreads();
#pragma unroll
    for (int c = 0; c < 2; ++c) {
      bf16x8 af[4], bw[4];
#pragma unroll
      for (int mt = 0; mt < 4; ++mt)
        af[mt] = *(const bf16x8*)(As + (wm * 64 + mt * 16 + l15) * 64 +
                                  c * 32 + quad * 8);
#pragma unroll
      for (int nt = 0; nt < 4; ++nt)
        bw[nt] = *(const bf16x8*)(Bs + (wn * 64 + nt * 16 + l15) * 64 +
                                  c * 32 + quad * 8);
#pragma unroll
      for (int mt = 0; mt < 4; ++mt)
#pragma unroll
        for (int nt = 0; nt < 4; ++nt)
          acc[mt][nt] = __builtin_amdgcn_mfma_f32_16x16x32_bf16(
              bw[nt], af[mt], acc[mt][nt], 0, 0, 0);
    }
    __syncthreads();
  }
#pragma unroll
  for (int mt = 0; mt < 4; ++mt) {
    int m_g = mtile * 128 + wm * 64 + mt * 16 + l15;
#pragma unroll
    for (int nt = 0; nt < 4; ++nt) {
      int n_g = nb * 128 + wn * 64 + nt * 16 + quad * 4;
      f32x4 a = acc[mt][nt];
      f32x4 xr = *(const f32x4*)(x + (size_t)m_g * 512 + n_g);
      f32x4 bb = *(const f32x4*)(bo + n_g);
      f32x4 o;
#pragma unroll
      for (int r = 0; r < 4; ++r)
        o[r] = a[r] + bb[r] + xr[r];
      *(f32x4*)(out + (size_t)m_g * 512 + n_g) = o;
    }
  }
}

extern "C" void kernel_launch(void* const* d_in, const int* in_sizes, int n_in,
                              void* d_out, int out_size, void* d_ws, size_t ws_size,
                              hipStream_t stream) {
  const float* x     = (const float*)d_in[0];
  const float* wq    = (const float*)d_in[1];
  const float* wk    = (const float*)d_in[2];
  const float* wv    = (const float*)d_in[3];
  const float* wo    = (const float*)d_in[4];
  const float* bo    = (const float*)d_in[5];
  const float* gamma = (const float*)d_in[6];
  const float* beta  = (const float*)d_in[7];
  float* out = (float*)d_out;
  char* ws = (char*)d_ws;
  const size_t SZ = (size_t)8192 * 512 * sizeof(bf16);  // 8 MB
  bf16* h   = (bf16*)(ws);          // aliased with Ao (h dead before attn)
  bf16* Ao  = (bf16*)(ws);
  bf16* Qg  = (bf16*)(ws + SZ);
  bf16* Kg  = (bf16*)(ws + 2 * SZ);
  bf16* Vtg = (bf16*)(ws + 3 * SZ);
  bf16* Wb  = (bf16*)(ws + 4 * SZ); // 4 x 512x512 bf16 = 2 MB (ws: 34 MB)

  ln_kernel<<<2560, 256, 0, stream>>>(x, gamma, beta, wq, wk, wv, wo, h, Wb);
  qkv_kernel<<<dim3(64, 12), 256, 0, stream>>>(h, Wb, Qg, Kg, Vtg);
  attn_kernel<<<512, 256, 0, stream>>>(Qg, Kg, Vtg, Ao);
  proj_kernel<<<dim3(64, 4), 256, 0, stream>>>(Ao, Wb + 3 * 262144, bo, x, out);
}